// Round 8
// baseline (1857.494 us; speedup 1.0000x reference)
//
#include <hip/hip_runtime.h>
#include <hip/hip_bf16.h>

// Problem constants: B=4, N=4096, DIM=1024; qkva = [B*N, 3*DIM]
#define SEQ_N 4096
#define BATCH 4
#define DIM 1024
#define M_ROWS (BATCH * SEQ_N)      // 16384
#define NCOLS (3 * DIM)             // 3072
#define KDIM DIM                    // 1024
#define CHUNK_L 16
#define NCHUNK (SEQ_N / CHUNK_L)    // 256
#define NCHANNEL (BATCH * DIM)      // 4096
#define GT 32                       // K / 32 k-tiles for the 256x256 GEMM
#define SCAN_BLOCKS (NCHUNK * BATCH)  // 1024 == 256 CU x 4 blocks/CU capacity

using short8 = __attribute__((ext_vector_type(8))) short;
using f32x4  = __attribute__((ext_vector_type(4))) float;

static __device__ __forceinline__ unsigned short f2bf(float f) {
    union { float f; unsigned u; } v; v.f = f;
    unsigned r = v.u + 0x7fffu + ((v.u >> 16) & 1u);   // round-to-nearest-even
    return (unsigned short)(r >> 16);
}
static __device__ __forceinline__ float bf2f(unsigned short s) {
    union { unsigned u; float f; } v; v.u = ((unsigned)s) << 16;
    return v.f;
}
static __device__ __forceinline__ float sigm(float x) {
    return 1.f / (1.f + __expf(-x));
}

// ---------------- fused: w fp32->bf16 (blocks 0..3071) + RMSNorm (blocks 3072..) ----
#define WCONV_BLOCKS 3072           // NCOLS*KDIM/4/256
__global__ __launch_bounds__(256) void pre_kernel(const float* __restrict__ w,
                                                  unsigned short* __restrict__ wb,
                                                  const float* __restrict__ x,
                                                  const float* __restrict__ gamma,
                                                  unsigned short* __restrict__ h) {
    const int bid = blockIdx.x;
    const int tid = threadIdx.x;
    if (bid < WCONV_BLOCKS) {
        const int i = bid * 256 + tid;
        float4 v = reinterpret_cast<const float4*>(w)[i];
        ushort4 o;
        o.x = f2bf(v.x); o.y = f2bf(v.y); o.z = f2bf(v.z); o.w = f2bf(v.w);
        reinterpret_cast<ushort4*>(wb)[i] = o;
        return;
    }
    const int row = bid - WCONV_BLOCKS;
    const float4 v = reinterpret_cast<const float4*>(x + (size_t)row * DIM)[tid];
    float ss = v.x * v.x + v.y * v.y + v.z * v.z + v.w * v.w;
#pragma unroll
    for (int off = 32; off >= 1; off >>= 1) ss += __shfl_xor(ss, off, 64);
    __shared__ float red[4];
    if ((tid & 63) == 0) red[tid >> 6] = ss;
    __syncthreads();
    const float tot = red[0] + red[1] + red[2] + red[3];
    const float scale = 32.0f / fmaxf(sqrtf(tot), 1e-12f);   // sqrt(1024)=32
    const float4 g = reinterpret_cast<const float4*>(gamma)[tid];
    ushort4 o;
    o.x = f2bf(v.x * scale * g.x);
    o.y = f2bf(v.y * scale * g.y);
    o.z = f2bf(v.z * scale * g.z);
    o.w = f2bf(v.w * scale * g.w);
    reinterpret_cast<ushort4*>(h + (size_t)row * DIM)[tid] = o;
}

// ---------------- GEMM (R5 known-good): C[m,e] = sum_k A[m,k]*B[e,k] ----
// 256x256 tile, BK=32, 4-deep LDS rotation, 8 waves (2Mx4N), barrier-minimal
// (one {vmcnt; s_barrier} per K-tile). T2 16B-granule XOR swizzle (source+read).
// mtile-major XCD swizzle (12 consecutive blocks share one L2-resident A-panel).
__global__ __launch_bounds__(512, 2) void gemm256_kernel(const unsigned short* __restrict__ A,
                                                         const unsigned short* __restrict__ B,
                                                         unsigned short* __restrict__ C) {
    __shared__ __align__(16) unsigned short sA[4][256][32];   // 64 KiB
    __shared__ __align__(16) unsigned short sB[4][256][32];   // 64 KiB

    const int tid  = threadIdx.x;
    const int lane = tid & 63;
    const int wave = tid >> 6;

    // mtile-major bijective XCD swizzle. nwg = 768 = 8 XCD * 96.
    const int orig = blockIdx.x;
    const int xcd  = orig & 7;
    const int q    = orig >> 3;           // 0..95
    const int mtile = xcd * 8 + q / 12;   // 0..63
    const int ntile = q % 12;             // 0..11
    const int row0 = mtile * 256;
    const int col0 = ntile * 256;

    const int wm = (wave >> 2) * 128;     // 0 or 128
    const int wn = (wave & 3) * 64;       // 0,64,128,192
    const int fr = lane & 15;             // frag row/col within 16x16
    const int kq = lane >> 4;             // k-quad (which 8 of K=32)
    const int kqx = kq ^ ((fr >> 1) & 3); // T2 swizzled granule (per-lane const)

    // staging: 512 thr x 16B = 8KB per unit; unit covers 128 rows; T2 source perm
    const int srow = tid >> 2;            // 0..127
    const int scol = ((tid & 3) ^ ((srow >> 1) & 3)) * 8;   // swizzled global granule
    const unsigned short* aSrc = A + (size_t)(row0 + srow) * KDIM + scol;
    const unsigned short* bSrc = B + (size_t)(col0 + srow) * KDIM + scol;
    unsigned short* sAf = &sA[0][0][0];
    unsigned short* sBf = &sB[0][0][0];
    const int sdst = tid * 8;             // linear LDS dest (element offset)

#define STAGE_A(bs, kt, u)                                                              \
    __builtin_amdgcn_global_load_lds(                                                   \
        (const __attribute__((address_space(1))) void*)(aSrc + (size_t)(u) * 128 * KDIM + (kt) * 32), \
        (__attribute__((address_space(3))) void*)(sAf + (bs) * 8192 + (u) * 4096 + sdst), 16, 0, 0);
#define STAGE_B(bs, kt, u)                                                              \
    __builtin_amdgcn_global_load_lds(                                                   \
        (const __attribute__((address_space(1))) void*)(bSrc + (size_t)(u) * 128 * KDIM + (kt) * 32), \
        (__attribute__((address_space(3))) void*)(sBf + (bs) * 8192 + (u) * 4096 + sdst), 16, 0, 0);

    f32x4 acc[8][4] = {};

    // prologue: stage tiles 0 and 1 (8 loads), wait for tile 0 (4 left in flight)
    STAGE_A(0, 0, 0); STAGE_A(0, 0, 1); STAGE_B(0, 0, 0); STAGE_B(0, 0, 1);
    STAGE_A(1, 1, 0); STAGE_A(1, 1, 1); STAGE_B(1, 1, 0); STAGE_B(1, 1, 1);
    asm volatile("s_waitcnt vmcnt(4)" ::: "memory");
    __builtin_amdgcn_sched_barrier(0);
    __builtin_amdgcn_s_barrier();

    // invariant entering tile t: tiles <= t landed (all waves); only t+1's loads outstanding
    for (int t = 0; t < GT; ++t) {
        const int b  = t & 3;
        const int bs = (t + 2) & 3;
        const bool st = (t + 2 < GT);
        const unsigned short* sAb = sAf + b * 8192;
        const unsigned short* sBb = sBf + b * 8192;

        short8 bfr[4], afr[4], afr2[4];
#pragma unroll
        for (int j = 0; j < 4; ++j)
            bfr[j] = *reinterpret_cast<const short8*>(sBb + (wn + j * 16 + fr) * 32 + kqx * 8);
#pragma unroll
        for (int i = 0; i < 4; ++i)
            afr[i] = *reinterpret_cast<const short8*>(sAb + (wm + i * 16 + fr) * 32 + kqx * 8);
#pragma unroll
        for (int i = 0; i < 4; ++i)
            afr2[i] = *reinterpret_cast<const short8*>(sAb + (wm + 64 + i * 16 + fr) * 32 + kqx * 8);

        if (st) { STAGE_A(bs, t + 2, 0); STAGE_A(bs, t + 2, 1);
                  STAGE_B(bs, t + 2, 0); STAGE_B(bs, t + 2, 1); }

        __builtin_amdgcn_s_setprio(1);
#pragma unroll
        for (int i = 0; i < 4; ++i)
#pragma unroll
            for (int j = 0; j < 4; ++j)
                acc[i][j] = __builtin_amdgcn_mfma_f32_16x16x32_bf16(afr[i], bfr[j], acc[i][j], 0, 0, 0);
#pragma unroll
        for (int i = 0; i < 4; ++i)
#pragma unroll
            for (int j = 0; j < 4; ++j)
                acc[4 + i][j] = __builtin_amdgcn_mfma_f32_16x16x32_bf16(afr2[i], bfr[j], acc[4 + i][j], 0, 0, 0);
        __builtin_amdgcn_s_setprio(0);

        // single per-tile publish: tile t+1's loads must land before next tile's reads
        if (t < GT - 2) {
            asm volatile("s_waitcnt vmcnt(4)" ::: "memory");
        } else if (t == GT - 2) {
            asm volatile("s_waitcnt vmcnt(0)" ::: "memory");
        }
        __builtin_amdgcn_sched_barrier(0);
        __builtin_amdgcn_s_barrier();
    }
#undef STAGE_A
#undef STAGE_B

    // epilogue: C/D layout col=lane&15, row=(lane>>4)*4+reg
#pragma unroll
    for (int i = 0; i < 8; ++i) {
#pragma unroll
        for (int j = 0; j < 4; ++j) {
#pragma unroll
            for (int r = 0; r < 4; ++r) {
                int row = row0 + wm + i * 16 + kq * 4 + r;
                int col = col0 + wn + j * 16 + fr;
                C[(size_t)row * NCOLS + col] = f2bf(acc[i][j][r]);
            }
        }
    }
}

// ---------------- software grid barrier (capacity-guaranteed co-residency) ----
// Safe iff grid <= resident capacity. Grid = 1024 = 256 CU x 4 blocks/CU, and
// __launch_bounds__(256,4) forces <=128 VGPR => >=4 blocks/CU. No dependence on
// dispatch ORDER (G16): every block is resident before any can spin forever.
static __device__ __forceinline__ void grid_bar(unsigned* cnt) {
    __syncthreads();
    if (threadIdx.x == 0) {
        __threadfence();   // publish this block's prior writes (device scope)
        __hip_atomic_fetch_add(cnt, 1u, __ATOMIC_RELEASE, __HIP_MEMORY_SCOPE_AGENT);
        while (__hip_atomic_load(cnt, __ATOMIC_ACQUIRE, __HIP_MEMORY_SCOPE_AGENT)
               < (unsigned)SCAN_BLOCKS)
            __builtin_amdgcn_s_sleep(8);
        __threadfence();   // make others' writes visible before we proceed
    }
    __syncthreads();
}

// ---------------- Fused scan: one kernel, 3 phases, 2 software grid barriers.
// grid = 1024 blocks (c = bid&255, b = bid>>8), 256 thr, 4 channels/thread.
// Phase 1: load chunk kv/a into REGISTERS (16x2 ushort4, static idx), compute
//          per-chunk aggregates, coalesced [c][ch] float4 writes.
// Phase 2: blocks 0..15 scan the 256 chunk aggregates per channel (coalesced).
// Phase 3: read Sin + q only; kv/a already in registers -> out = q*y.
// Eliminates apply's 67MB kv/a re-read and two kernel-launch drains.
__global__ __launch_bounds__(256, 4) void scan_fused_kernel(const unsigned short* __restrict__ qkva,
                                                            float* __restrict__ Aagg,
                                                            float* __restrict__ Yagg,
                                                            float* __restrict__ Sin,
                                                            float* __restrict__ out,
                                                            unsigned* __restrict__ barcnt) {
    const int bid = blockIdx.x;
    const int c = bid & (NCHUNK - 1);
    const int b = bid >> 8;
    const int tid = threadIdx.x;
    const int d4 = tid * 4;
    const unsigned short* base = qkva + ((size_t)b * SEQ_N + c * CHUNK_L) * NCOLS;

    // ---- phase 1: registers hold the whole chunk's kv/a slices ----
    ushort4 kvr[CHUNK_L], ar[CHUNK_L];
#pragma unroll
    for (int n = 0; n < CHUNK_L; ++n) {
        kvr[n] = *reinterpret_cast<const ushort4*>(base + (size_t)n * NCOLS + DIM + d4);
        ar[n]  = *reinterpret_cast<const ushort4*>(base + (size_t)n * NCOLS + 2 * DIM + d4);
    }
    float s0f = 0.f, s1f = 0.f, s2f = 0.f, s3f = 0.f;
    float A0 = 1.f, A1 = 1.f, A2 = 1.f, A3 = 1.f;
#pragma unroll
    for (int n = 0; n < CHUNK_L; ++n) {
        const float a0 = sigm(bf2f(ar[n].x)), a1 = sigm(bf2f(ar[n].y));
        const float a2 = sigm(bf2f(ar[n].z)), a3 = sigm(bf2f(ar[n].w));
        s0f = fmaf(a0, s0f, bf2f(kvr[n].x)); A0 *= a0;
        s1f = fmaf(a1, s1f, bf2f(kvr[n].y)); A1 *= a1;
        s2f = fmaf(a2, s2f, bf2f(kvr[n].z)); A2 *= a2;
        s3f = fmaf(a3, s3f, bf2f(kvr[n].w)); A3 *= a3;
    }
    {
        const size_t idx = (size_t)c * NCHANNEL + b * DIM + d4;
        float4 Ao, Yo;
        Ao.x = A0; Ao.y = A1; Ao.z = A2; Ao.w = A3;
        Yo.x = s0f; Yo.y = s1f; Yo.z = s2f; Yo.w = s3f;
        *reinterpret_cast<float4*>(&Aagg[idx]) = Ao;
        *reinterpret_cast<float4*>(&Yagg[idx]) = Yo;
    }
    grid_bar(&barcnt[0]);

    // ---- phase 2: 16 blocks scan chunk aggregates (coalesced per c-step) ----
    if (bid < 16) {
        const int ch = bid * 256 + tid;
        float ss = 0.f;
#pragma unroll 8
        for (int cc = 0; cc < NCHUNK; ++cc) {
            const float Ac = Aagg[(size_t)cc * NCHANNEL + ch];
            const float Yc = Yagg[(size_t)cc * NCHANNEL + ch];
            Sin[(size_t)cc * NCHANNEL + ch] = ss;
            ss = fmaf(Ac, ss, Yc);
        }
    }
    grid_bar(&barcnt[1]);

    // ---- phase 3: rescan from registers with correct entry state ----
    const float4 si = *reinterpret_cast<const float4*>(&Sin[(size_t)c * NCHANNEL + b * DIM + d4]);
    float s0 = si.x, s1 = si.y, s2 = si.z, s3 = si.w;
    float* obase = out + ((size_t)b * SEQ_N + c * CHUNK_L) * DIM;
#pragma unroll
    for (int n = 0; n < CHUNK_L; ++n) {
        const ushort4 qu = *reinterpret_cast<const ushort4*>(base + (size_t)n * NCOLS + d4);
        const float a0 = sigm(bf2f(ar[n].x)), a1 = sigm(bf2f(ar[n].y));
        const float a2 = sigm(bf2f(ar[n].z)), a3 = sigm(bf2f(ar[n].w));
        s0 = fmaf(a0, s0, bf2f(kvr[n].x));
        s1 = fmaf(a1, s1, bf2f(kvr[n].y));
        s2 = fmaf(a2, s2, bf2f(kvr[n].z));
        s3 = fmaf(a3, s3, bf2f(kvr[n].w));
        float4 o;
        o.x = bf2f(qu.x) * s0; o.y = bf2f(qu.y) * s1;
        o.z = bf2f(qu.z) * s2; o.w = bf2f(qu.w) * s3;
        *reinterpret_cast<float4*>(&obase[(size_t)n * DIM + d4]) = o;
    }
}

extern "C" void kernel_launch(void* const* d_in, const int* in_sizes, int n_in,
                              void* d_out, int out_size, void* d_ws, size_t ws_size,
                              hipStream_t stream) {
    const float* x     = (const float*)d_in[0];   // [4,4096,1024]
    const float* w     = (const float*)d_in[1];   // [3072,1024]
    const float* gamma = (const float*)d_in[2];   // [1024]
    float* out = (float*)d_out;                   // [4,4096,1024]

    char* ws = (char*)d_ws;
    unsigned short* wb   = (unsigned short*)(ws);                 // 6,291,456 B
    unsigned short* h    = (unsigned short*)(ws + 6291456);       // 33,554,432 B
    unsigned short* qkva = (unsigned short*)(ws + 39845888);      // 100,663,296 B -> ends 140,509,184
    // scan temporaries alias the h region (h is dead after the GEMM):
    float* Aagg = (float*)(ws + 6291456);                         // 4 MB
    float* Yagg = (float*)(ws + 6291456 + 4194304);               // 4 MB
    float* Sin  = (float*)(ws + 6291456 + 8388608);               // 4 MB
    unsigned* barcnt = (unsigned*)(ws + 140509184);               // 8 B (R6 proved ws >= 148.9MB)

    pre_kernel<<<WCONV_BLOCKS + M_ROWS, 256, 0, stream>>>(w, wb, x, gamma, h);
    gemm256_kernel<<<(M_ROWS / 256) * (NCOLS / 256), 512, 0, stream>>>(h, wb, qkva);
    hipMemsetAsync(barcnt, 0, 2 * sizeof(unsigned), stream);
    scan_fused_kernel<<<SCAN_BLOCKS, 256, 0, stream>>>(qkva, Aagg, Yagg, Sin, out, barcnt);
}

// Round 9
// 520.943 us; speedup vs baseline: 3.5656x; 3.5656x over previous
//
#include <hip/hip_runtime.h>
#include <hip/hip_bf16.h>

// Problem constants: B=4, N=4096, DIM=1024; qkva = [B*N, 3*DIM]
#define SEQ_N 4096
#define BATCH 4
#define DIM 1024
#define M_ROWS (BATCH * SEQ_N)      // 16384
#define NCOLS (3 * DIM)             // 3072
#define KDIM DIM                    // 1024
#define CHUNK_L 16
#define NCHUNK (SEQ_N / CHUNK_L)    // 256
#define NCHANNEL (BATCH * DIM)      // 4096
#define GT 32                       // K / 32 k-tiles for the 256x256 GEMM
#define SCAN_BLOCKS (NCHUNK * BATCH)  // 1024 == 256 CU x 4 blocks/CU capacity

using short8 = __attribute__((ext_vector_type(8))) short;
using f32x4  = __attribute__((ext_vector_type(4))) float;

static __device__ __forceinline__ unsigned short f2bf(float f) {
    union { float f; unsigned u; } v; v.f = f;
    unsigned r = v.u + 0x7fffu + ((v.u >> 16) & 1u);   // round-to-nearest-even
    return (unsigned short)(r >> 16);
}
static __device__ __forceinline__ float bf2f(unsigned short s) {
    union { unsigned u; float f; } v; v.u = ((unsigned)s) << 16;
    return v.f;
}
static __device__ __forceinline__ float sigm(float x) {
    return 1.f / (1.f + __expf(-x));
}

// ---------------- fused: w fp32->bf16 (blocks 0..3071) + RMSNorm (blocks 3072..) ----
#define WCONV_BLOCKS 3072           // NCOLS*KDIM/4/256
__global__ __launch_bounds__(256) void pre_kernel(const float* __restrict__ w,
                                                  unsigned short* __restrict__ wb,
                                                  const float* __restrict__ x,
                                                  const float* __restrict__ gamma,
                                                  unsigned short* __restrict__ h) {
    const int bid = blockIdx.x;
    const int tid = threadIdx.x;
    if (bid < WCONV_BLOCKS) {
        const int i = bid * 256 + tid;
        float4 v = reinterpret_cast<const float4*>(w)[i];
        ushort4 o;
        o.x = f2bf(v.x); o.y = f2bf(v.y); o.z = f2bf(v.z); o.w = f2bf(v.w);
        reinterpret_cast<ushort4*>(wb)[i] = o;
        return;
    }
    const int row = bid - WCONV_BLOCKS;
    const float4 v = reinterpret_cast<const float4*>(x + (size_t)row * DIM)[tid];
    float ss = v.x * v.x + v.y * v.y + v.z * v.z + v.w * v.w;
#pragma unroll
    for (int off = 32; off >= 1; off >>= 1) ss += __shfl_xor(ss, off, 64);
    __shared__ float red[4];
    if ((tid & 63) == 0) red[tid >> 6] = ss;
    __syncthreads();
    const float tot = red[0] + red[1] + red[2] + red[3];
    const float scale = 32.0f / fmaxf(sqrtf(tot), 1e-12f);   // sqrt(1024)=32
    const float4 g = reinterpret_cast<const float4*>(gamma)[tid];
    ushort4 o;
    o.x = f2bf(v.x * scale * g.x);
    o.y = f2bf(v.y * scale * g.y);
    o.z = f2bf(v.z * scale * g.z);
    o.w = f2bf(v.w * scale * g.w);
    reinterpret_cast<ushort4*>(h + (size_t)row * DIM)[tid] = o;
}

// ---------------- GEMM (R5 known-good): C[m,e] = sum_k A[m,k]*B[e,k] ----
// 256x256 tile, BK=32, 4-deep LDS rotation, 8 waves (2Mx4N), barrier-minimal
// (one {vmcnt; s_barrier} per K-tile). T2 16B-granule XOR swizzle (source+read).
// mtile-major XCD swizzle (12 consecutive blocks share one L2-resident A-panel).
__global__ __launch_bounds__(512, 2) void gemm256_kernel(const unsigned short* __restrict__ A,
                                                         const unsigned short* __restrict__ B,
                                                         unsigned short* __restrict__ C) {
    __shared__ __align__(16) unsigned short sA[4][256][32];   // 64 KiB
    __shared__ __align__(16) unsigned short sB[4][256][32];   // 64 KiB

    const int tid  = threadIdx.x;
    const int lane = tid & 63;
    const int wave = tid >> 6;

    // mtile-major bijective XCD swizzle. nwg = 768 = 8 XCD * 96.
    const int orig = blockIdx.x;
    const int xcd  = orig & 7;
    const int q    = orig >> 3;           // 0..95
    const int mtile = xcd * 8 + q / 12;   // 0..63
    const int ntile = q % 12;             // 0..11
    const int row0 = mtile * 256;
    const int col0 = ntile * 256;

    const int wm = (wave >> 2) * 128;     // 0 or 128
    const int wn = (wave & 3) * 64;       // 0,64,128,192
    const int fr = lane & 15;             // frag row/col within 16x16
    const int kq = lane >> 4;             // k-quad (which 8 of K=32)
    const int kqx = kq ^ ((fr >> 1) & 3); // T2 swizzled granule (per-lane const)

    // staging: 512 thr x 16B = 8KB per unit; unit covers 128 rows; T2 source perm
    const int srow = tid >> 2;            // 0..127
    const int scol = ((tid & 3) ^ ((srow >> 1) & 3)) * 8;   // swizzled global granule
    const unsigned short* aSrc = A + (size_t)(row0 + srow) * KDIM + scol;
    const unsigned short* bSrc = B + (size_t)(col0 + srow) * KDIM + scol;
    unsigned short* sAf = &sA[0][0][0];
    unsigned short* sBf = &sB[0][0][0];
    const int sdst = tid * 8;             // linear LDS dest (element offset)

#define STAGE_A(bs, kt, u)                                                              \
    __builtin_amdgcn_global_load_lds(                                                   \
        (const __attribute__((address_space(1))) void*)(aSrc + (size_t)(u) * 128 * KDIM + (kt) * 32), \
        (__attribute__((address_space(3))) void*)(sAf + (bs) * 8192 + (u) * 4096 + sdst), 16, 0, 0);
#define STAGE_B(bs, kt, u)                                                              \
    __builtin_amdgcn_global_load_lds(                                                   \
        (const __attribute__((address_space(1))) void*)(bSrc + (size_t)(u) * 128 * KDIM + (kt) * 32), \
        (__attribute__((address_space(3))) void*)(sBf + (bs) * 8192 + (u) * 4096 + sdst), 16, 0, 0);

    f32x4 acc[8][4] = {};

    // prologue: stage tiles 0 and 1 (8 loads), wait for tile 0 (4 left in flight)
    STAGE_A(0, 0, 0); STAGE_A(0, 0, 1); STAGE_B(0, 0, 0); STAGE_B(0, 0, 1);
    STAGE_A(1, 1, 0); STAGE_A(1, 1, 1); STAGE_B(1, 1, 0); STAGE_B(1, 1, 1);
    asm volatile("s_waitcnt vmcnt(4)" ::: "memory");
    __builtin_amdgcn_sched_barrier(0);
    __builtin_amdgcn_s_barrier();

    // invariant entering tile t: tiles <= t landed (all waves); only t+1's loads outstanding
    for (int t = 0; t < GT; ++t) {
        const int b  = t & 3;
        const int bs = (t + 2) & 3;
        const bool st = (t + 2 < GT);
        const unsigned short* sAb = sAf + b * 8192;
        const unsigned short* sBb = sBf + b * 8192;

        short8 bfr[4], afr[4], afr2[4];
#pragma unroll
        for (int j = 0; j < 4; ++j)
            bfr[j] = *reinterpret_cast<const short8*>(sBb + (wn + j * 16 + fr) * 32 + kqx * 8);
#pragma unroll
        for (int i = 0; i < 4; ++i)
            afr[i] = *reinterpret_cast<const short8*>(sAb + (wm + i * 16 + fr) * 32 + kqx * 8);
#pragma unroll
        for (int i = 0; i < 4; ++i)
            afr2[i] = *reinterpret_cast<const short8*>(sAb + (wm + 64 + i * 16 + fr) * 32 + kqx * 8);

        if (st) { STAGE_A(bs, t + 2, 0); STAGE_A(bs, t + 2, 1);
                  STAGE_B(bs, t + 2, 0); STAGE_B(bs, t + 2, 1); }

        __builtin_amdgcn_s_setprio(1);
#pragma unroll
        for (int i = 0; i < 4; ++i)
#pragma unroll
            for (int j = 0; j < 4; ++j)
                acc[i][j] = __builtin_amdgcn_mfma_f32_16x16x32_bf16(afr[i], bfr[j], acc[i][j], 0, 0, 0);
#pragma unroll
        for (int i = 0; i < 4; ++i)
#pragma unroll
            for (int j = 0; j < 4; ++j)
                acc[4 + i][j] = __builtin_amdgcn_mfma_f32_16x16x32_bf16(afr2[i], bfr[j], acc[4 + i][j], 0, 0, 0);
        __builtin_amdgcn_s_setprio(0);

        // single per-tile publish: tile t+1's loads must land before next tile's reads
        if (t < GT - 2) {
            asm volatile("s_waitcnt vmcnt(4)" ::: "memory");
        } else if (t == GT - 2) {
            asm volatile("s_waitcnt vmcnt(0)" ::: "memory");
        }
        __builtin_amdgcn_sched_barrier(0);
        __builtin_amdgcn_s_barrier();
    }
#undef STAGE_A
#undef STAGE_B

    // epilogue: C/D layout col=lane&15, row=(lane>>4)*4+reg
#pragma unroll
    for (int i = 0; i < 8; ++i) {
#pragma unroll
        for (int j = 0; j < 4; ++j) {
#pragma unroll
            for (int r = 0; r < 4; ++r) {
                int row = row0 + wm + i * 16 + kq * 4 + r;
                int col = col0 + wn + j * 16 + fr;
                C[(size_t)row * NCOLS + col] = f2bf(acc[i][j][r]);
            }
        }
    }
}

// ---------------- software grid barrier v2 (relaxed spin) ----
// Safe iff grid <= resident capacity: grid = 1024 = 256 CU x 4 blocks/CU and
// __launch_bounds__(256,4) caps VGPR <= 128 => >= 4 blocks/CU. No dispatch-
// order assumption (G16): all blocks resident before any can spin forever.
// R8 LESSON: polling with ACQUIRE at agent scope emits a per-poll cache
// invalidate (agent-scope buffer_inv = per-XCD L2 wipe) -> 1024 spinners
// continuously invalidated all L2s, collapsing chip BW to 131 GB/s. Fix:
// RELAXED polls (plain coherent-point load, no invalidate), then exactly ONE
// acquire fence (__threadfence) per block after the spin exits.
static __device__ __forceinline__ void grid_bar(unsigned* cnt) {
    __syncthreads();
    if (threadIdx.x == 0) {
        // release fetch_add: writes back this XCD's L2 (publishes block writes)
        __hip_atomic_fetch_add(cnt, 1u, __ATOMIC_RELEASE, __HIP_MEMORY_SCOPE_AGENT);
        while (__hip_atomic_load(cnt, __ATOMIC_RELAXED, __HIP_MEMORY_SCOPE_AGENT)
               < (unsigned)SCAN_BLOCKS)
            __builtin_amdgcn_s_sleep(32);   // ~2048 cy between polls
        __threadfence();   // single acquire: invalidate once, see others' writes
    }
    __syncthreads();
}

// ---------------- Fused scan: one kernel, 3 phases, 2 software grid barriers.
// grid = 1024 blocks (c = bid&255, b = bid>>8), 256 thr, 4 channels/thread.
// Phase 1: load chunk kv/a into REGISTERS (16x2 ushort4, static idx), compute
//          per-chunk aggregates, coalesced [c][ch] float4 writes.
// Phase 2: blocks 0..15 scan the 256 chunk aggregates per channel (coalesced).
// Phase 3: read Sin + q only; kv/a already in registers -> out = q*y.
// Eliminates apply's 67MB kv/a re-read and two kernel-launch drains.
__global__ __launch_bounds__(256, 4) void scan_fused_kernel(const unsigned short* __restrict__ qkva,
                                                            float* __restrict__ Aagg,
                                                            float* __restrict__ Yagg,
                                                            float* __restrict__ Sin,
                                                            float* __restrict__ out,
                                                            unsigned* __restrict__ barcnt) {
    const int bid = blockIdx.x;
    const int c = bid & (NCHUNK - 1);
    const int b = bid >> 8;
    const int tid = threadIdx.x;
    const int d4 = tid * 4;
    const unsigned short* base = qkva + ((size_t)b * SEQ_N + c * CHUNK_L) * NCOLS;

    // ---- phase 1: registers hold the whole chunk's kv/a slices ----
    ushort4 kvr[CHUNK_L], ar[CHUNK_L];
#pragma unroll
    for (int n = 0; n < CHUNK_L; ++n) {
        kvr[n] = *reinterpret_cast<const ushort4*>(base + (size_t)n * NCOLS + DIM + d4);
        ar[n]  = *reinterpret_cast<const ushort4*>(base + (size_t)n * NCOLS + 2 * DIM + d4);
    }
    float s0f = 0.f, s1f = 0.f, s2f = 0.f, s3f = 0.f;
    float A0 = 1.f, A1 = 1.f, A2 = 1.f, A3 = 1.f;
#pragma unroll
    for (int n = 0; n < CHUNK_L; ++n) {
        const float a0 = sigm(bf2f(ar[n].x)), a1 = sigm(bf2f(ar[n].y));
        const float a2 = sigm(bf2f(ar[n].z)), a3 = sigm(bf2f(ar[n].w));
        s0f = fmaf(a0, s0f, bf2f(kvr[n].x)); A0 *= a0;
        s1f = fmaf(a1, s1f, bf2f(kvr[n].y)); A1 *= a1;
        s2f = fmaf(a2, s2f, bf2f(kvr[n].z)); A2 *= a2;
        s3f = fmaf(a3, s3f, bf2f(kvr[n].w)); A3 *= a3;
    }
    {
        const size_t idx = (size_t)c * NCHANNEL + b * DIM + d4;
        float4 Ao, Yo;
        Ao.x = A0; Ao.y = A1; Ao.z = A2; Ao.w = A3;
        Yo.x = s0f; Yo.y = s1f; Yo.z = s2f; Yo.w = s3f;
        *reinterpret_cast<float4*>(&Aagg[idx]) = Ao;
        *reinterpret_cast<float4*>(&Yagg[idx]) = Yo;
    }
    grid_bar(&barcnt[0]);

    // ---- phase 2: 16 blocks scan chunk aggregates (coalesced per c-step) ----
    if (bid < 16) {
        const int ch = bid * 256 + tid;
        float ss = 0.f;
#pragma unroll 8
        for (int cc = 0; cc < NCHUNK; ++cc) {
            const float Ac = Aagg[(size_t)cc * NCHANNEL + ch];
            const float Yc = Yagg[(size_t)cc * NCHANNEL + ch];
            Sin[(size_t)cc * NCHANNEL + ch] = ss;
            ss = fmaf(Ac, ss, Yc);
        }
    }
    grid_bar(&barcnt[1]);

    // ---- phase 3: rescan from registers with correct entry state ----
    const float4 si = *reinterpret_cast<const float4*>(&Sin[(size_t)c * NCHANNEL + b * DIM + d4]);
    float s0 = si.x, s1 = si.y, s2 = si.z, s3 = si.w;
    float* obase = out + ((size_t)b * SEQ_N + c * CHUNK_L) * DIM;
#pragma unroll
    for (int n = 0; n < CHUNK_L; ++n) {
        const ushort4 qu = *reinterpret_cast<const ushort4*>(base + (size_t)n * NCOLS + d4);
        const float a0 = sigm(bf2f(ar[n].x)), a1 = sigm(bf2f(ar[n].y));
        const float a2 = sigm(bf2f(ar[n].z)), a3 = sigm(bf2f(ar[n].w));
        s0 = fmaf(a0, s0, bf2f(kvr[n].x));
        s1 = fmaf(a1, s1, bf2f(kvr[n].y));
        s2 = fmaf(a2, s2, bf2f(kvr[n].z));
        s3 = fmaf(a3, s3, bf2f(kvr[n].w));
        float4 o;
        o.x = bf2f(qu.x) * s0; o.y = bf2f(qu.y) * s1;
        o.z = bf2f(qu.z) * s2; o.w = bf2f(qu.w) * s3;
        *reinterpret_cast<float4*>(&obase[(size_t)n * DIM + d4]) = o;
    }
}

extern "C" void kernel_launch(void* const* d_in, const int* in_sizes, int n_in,
                              void* d_out, int out_size, void* d_ws, size_t ws_size,
                              hipStream_t stream) {
    const float* x     = (const float*)d_in[0];   // [4,4096,1024]
    const float* w     = (const float*)d_in[1];   // [3072,1024]
    const float* gamma = (const float*)d_in[2];   // [1024]
    float* out = (float*)d_out;                   // [4,4096,1024]

    char* ws = (char*)d_ws;
    unsigned short* wb   = (unsigned short*)(ws);                 // 6,291,456 B
    unsigned short* h    = (unsigned short*)(ws + 6291456);       // 33,554,432 B
    unsigned short* qkva = (unsigned short*)(ws + 39845888);      // 100,663,296 B -> ends 140,509,184
    // scan temporaries alias the h region (h is dead after the GEMM):
    float* Aagg = (float*)(ws + 6291456);                         // 4 MB
    float* Yagg = (float*)(ws + 6291456 + 4194304);               // 4 MB
    float* Sin  = (float*)(ws + 6291456 + 8388608);               // 4 MB
    unsigned* barcnt = (unsigned*)(ws + 140509184);               // 8 B

    pre_kernel<<<WCONV_BLOCKS + M_ROWS, 256, 0, stream>>>(w, wb, x, gamma, h);
    gemm256_kernel<<<(M_ROWS / 256) * (NCOLS / 256), 512, 0, stream>>>(h, wb, qkva);
    hipMemsetAsync(barcnt, 0, 2 * sizeof(unsigned), stream);
    scan_fused_kernel<<<SCAN_BLOCKS, 256, 0, stream>>>(qkva, Aagg, Yagg, Sin, out, barcnt);
}